// Round 1
// baseline (228.306 us; speedup 1.0000x reference)
//
#include <hip/hip_runtime.h>
#include <cfloat>
#include <cmath>

#define HW 25600      // 160*160
#define WIDTH 160
#define NB 4
#define NC 128

__device__ __forceinline__ float gelu_exact(float x) {
    return 0.5f * x * (1.f + erff(x * 0.70710678118654752f));
}
__device__ __forceinline__ float sigmoidf_(float x) {
    return 1.f / (1.f + expf(-x));
}

// ---------------- K1: per-plane means (tau*512 + b*128 + c) ----------------
__global__ __launch_bounds__(256) void mean_kernel(const float* __restrict__ RGB,
                                                   const float* __restrict__ T,
                                                   float* __restrict__ means) {
    int p = blockIdx.x;  // 0..1023
    const float* src = (p < 512) ? (RGB + (size_t)p * HW)
                                 : (T + (size_t)(p - 512) * HW);
    const float4* s4 = (const float4*)src;
    float s = 0.f;
    for (int i = threadIdx.x; i < HW / 4; i += 256) {
        float4 v = s4[i];
        s += (v.x + v.y) + (v.z + v.w);
    }
    for (int off = 32; off; off >>= 1) s += __shfl_down(s, off);
    __shared__ float r[4];
    if ((threadIdx.x & 63) == 0) r[threadIdx.x >> 6] = s;
    __syncthreads();
    if (threadIdx.x == 0) means[p] = (r[0] + r[1] + r[2] + r[3]) * (1.f / (float)HW);
}

// ---------------- K2: feature-pool MLP + L2-normalize, per (tau,b) ----------------
__global__ __launch_bounds__(256) void mlp_kernel(const float* __restrict__ means,
                                                  const float* __restrict__ dww,
                                                  const float* __restrict__ dwb,
                                                  const float* __restrict__ uww,
                                                  const float* __restrict__ uwb,
                                                  float* __restrict__ ynorm) {
    int tb = blockIdx.x;  // tau*4 + b
    int t = threadIdx.x;
    __shared__ float sm[128];
    __shared__ float sh[256];
    __shared__ float zz[256];
    __shared__ float r4[4];
    if (t < 128) sm[t] = means[tb * 128 + t];
    __syncthreads();
    // down proj, hidden j = t (256 hidden)
    float a = dwb[t];
    const float* wrow = dww + t * 128;
    for (int c = 0; c < 128; ++c) a += wrow[c] * sm[c];
    sh[t] = gelu_exact(a);
    __syncthreads();
    // up proj: output c = t&127, half-split over j
    int c = t & 127, half = t >> 7;
    float z = 0.f;
    const float* urow = uww + c * 256 + half * 128;
    const float* hh = sh + half * 128;
    for (int j = 0; j < 128; ++j) z += urow[j] * hh[j];
    zz[t] = z;
    __syncthreads();
    float y = 0.f;
    if (t < 128) y = zz[t] + zz[t + 128] + uwb[t];
    float p = y * y;  // 0 for t>=128
    for (int off = 32; off; off >>= 1) p += __shfl_down(p, off);
    if ((t & 63) == 0) r4[t >> 6] = p;
    __syncthreads();
    float nrm = sqrtf(r4[0] + r4[1] + r4[2] + r4[3]);
    if (t < 128) ynorm[tb * 128 + t] = y / nrm;
}

// ---------------- K3: gated grouped 7x7 conv + spatial max (never materialized) ----------------
#define TW 166
#define TH 38
__global__ __launch_bounds__(256) void conv_max_kernel(const float* __restrict__ RGB,
                                                       const float* __restrict__ T,
                                                       const float* __restrict__ dww,
                                                       const float* __restrict__ ynorm,
                                                       float* __restrict__ part) {
    int yt = blockIdx.x;  // 0..4
    int g  = blockIdx.y;  // 0..127
    int b  = blockIdx.z;  // 0..3
    int t  = threadIdx.x;
    __shared__ float tile[2 * TH * TW];   // ~50.5 KB
    __shared__ float wsm[196];
    __shared__ float r0s[4], r1s[4];
    // stage the group's 2x2x7x7 weights: dw_w[(2g+ol)*98 + i*49 + ky*7 + kx] = dww[g*196 + ...]
    for (int i = t; i < 196; i += 256) wsm[i] = dww[g * 196 + i];
    // gates (uniform across block); cross_gate[b,c]=sigmoid(128*yr[j][j]*yt[j][k]), idx=b*128+c,k=idx>>2,j=idx&3
    int ic0 = 2 * g;
    int c0 = ic0 & 127, c1 = (ic0 + 1) & 127;
    const float* base = (ic0 < 128) ? RGB : T;  // both group channels are same modality
    const float* plane0 = base + ((size_t)(b * 128 + c0)) * HW;
    const float* plane1 = base + ((size_t)(b * 128 + c1)) * HW;
    int i0 = b * 128 + c0, i1 = b * 128 + c1;
    int j0 = i0 & 3, k0 = i0 >> 2, j1 = i1 & 3, k1 = i1 >> 2;
    float gate0 = sigmoidf_(128.f * ynorm[j0 * 128 + j0] * ynorm[512 + j0 * 128 + k0]);
    float gate1 = sigmoidf_(128.f * ynorm[j1 * 128 + j1] * ynorm[512 + j1 * 128 + k1]);
    // stage gated, zero-padded input tile (2 channels, 38 rows x 166 cols)
    int y0 = yt * 32 - 3;
    for (int i = t; i < 2 * TH * TW; i += 256) {
        int chl = i / (TH * TW);
        int rem = i - chl * (TH * TW);
        int row = rem / TW;
        int col = rem - row * TW;
        int gy = y0 + row, gx = col - 3;
        float v = 0.f;
        if (gy >= 0 && gy < 160 && gx >= 0 && gx < 160) {
            const float* pl = chl ? plane1 : plane0;
            float gt = chl ? gate1 : gate0;
            v = pl[gy * WIDTH + gx] * gt;
        }
        tile[i] = v;
    }
    __syncthreads();
    // each thread: 5 x-outputs x 4 y-outputs x 2 out-channels
    int xq = (t & 31) * 5;
    int yg = (t >> 5) * 4;
    float acc[2][4][5];
    #pragma unroll
    for (int o = 0; o < 2; ++o)
        #pragma unroll
        for (int i = 0; i < 4; ++i)
            #pragma unroll
            for (int j = 0; j < 5; ++j) acc[o][i][j] = 0.f;
    #pragma unroll
    for (int ky = 0; ky < 7; ++ky) {
        float w0[2][7], w1[2][7];
        #pragma unroll
        for (int ii = 0; ii < 2; ++ii)
            #pragma unroll
            for (int kx = 0; kx < 7; ++kx) {
                w0[ii][kx] = wsm[ii * 49 + ky * 7 + kx];
                w1[ii][kx] = wsm[98 + ii * 49 + ky * 7 + kx];
            }
        #pragma unroll
        for (int oy = 0; oy < 4; ++oy) {
            int row = yg + oy + ky;
            const float* t0 = tile + row * TW + xq;
            const float* t1 = tile + TH * TW + row * TW + xq;
            float win0[11], win1[11];
            #pragma unroll
            for (int j = 0; j < 11; ++j) { win0[j] = t0[j]; win1[j] = t1[j]; }
            #pragma unroll
            for (int kx = 0; kx < 7; ++kx) {
                #pragma unroll
                for (int ox = 0; ox < 5; ++ox) {
                    acc[0][oy][ox] += w0[0][kx] * win0[ox + kx] + w0[1][kx] * win1[ox + kx];
                    acc[1][oy][ox] += w1[0][kx] * win0[ox + kx] + w1[1][kx] * win1[ox + kx];
                }
            }
        }
    }
    float m0 = -FLT_MAX, m1 = -FLT_MAX;
    #pragma unroll
    for (int i = 0; i < 4; ++i)
        #pragma unroll
        for (int j = 0; j < 5; ++j) {
            m0 = fmaxf(m0, acc[0][i][j]);
            m1 = fmaxf(m1, acc[1][i][j]);
        }
    for (int off = 32; off; off >>= 1) {
        m0 = fmaxf(m0, __shfl_down(m0, off));
        m1 = fmaxf(m1, __shfl_down(m1, off));
    }
    if ((t & 63) == 0) { r0s[t >> 6] = m0; r1s[t >> 6] = m1; }
    __syncthreads();
    if (t == 0) {
        m0 = fmaxf(fmaxf(r0s[0], r0s[1]), fmaxf(r0s[2], r0s[3]));
        m1 = fmaxf(fmaxf(r1s[0], r1s[1]), fmaxf(r1s[2], r1s[3]));
        int bb = ((b * 128 + g) * 5 + yt) * 2;
        part[bb] = m0;
        part[bb + 1] = m1;
    }
}

// ---------------- K4: max-reduce + channel-att MLP -> per-channel coefficients ----------------
__global__ __launch_bounds__(256) void att_kernel(const float* __restrict__ ynorm,
                                                  const float* __restrict__ part,
                                                  const float* __restrict__ dwb,
                                                  const float* __restrict__ cdw,
                                                  const float* __restrict__ cdb,
                                                  const float* __restrict__ cuw,
                                                  const float* __restrict__ cub,
                                                  const float* __restrict__ srw,
                                                  const float* __restrict__ stw,
                                                  float* __restrict__ coefs) {
    int t = threadIdx.x;
    __shared__ float scg[512];
    __shared__ float smax[1024];
    __shared__ float sh2[64];
    __shared__ float sfg[1024];
    for (int idx = t; idx < 512; idx += 256) {
        int kk = idx >> 2, j = idx & 3;
        scg[idx] = sigmoidf_(128.f * ynorm[j * 128 + j] * ynorm[512 + j * 128 + kk]);
    }
    for (int idx = t; idx < 1024; idx += 256) {
        int b = idx >> 8, o = idx & 255;
        int gg = o >> 1, oc = o & 1;
        const float* pp = part + ((b * 128 + gg) * 5) * 2 + oc;
        float m = pp[0];
        #pragma unroll
        for (int yt = 1; yt < 5; ++yt) m = fmaxf(m, pp[yt * 2]);
        smax[idx] = m + dwb[o];
    }
    __syncthreads();
    if (t < 64) {
        int b = t >> 4, j = t & 15;
        float a = cdb[j];
        const float* wrow = cdw + j * 256;
        const float* mx = smax + b * 256;
        for (int o = 0; o < 256; ++o) a += wrow[o] * mx[o];
        sh2[t] = gelu_exact(a);
    }
    __syncthreads();
    for (int idx = t; idx < 1024; idx += 256) {
        int b = idx >> 8, o = idx & 255;
        float z = cub[o];
        const float* ur = cuw + o * 16;
        const float* hh = sh2 + b * 16;
        #pragma unroll
        for (int j = 0; j < 16; ++j) z += ur[j] * hh[j];
        sfg[idx] = sigmoidf_(z);
    }
    __syncthreads();
    for (int idx = t; idx < 512; idx += 256) {
        int b = idx >> 7, c = idx & 127;
        float cgv = scg[idx];
        float ar = cgv * sfg[b * 256 + c] + 1.f - cgv;
        float at = cgv * sfg[b * 256 + 128 + c] + 1.f - cgv;
        coefs[idx] = ar;                 // alpha_r
        coefs[512 + idx] = at;           // alpha_t
        coefs[1024 + idx] = ar * srw[c]; // wr = alpha_r * sr_w
        coefs[1536 + idx] = at * stw[c]; // wt = alpha_t * st_w
    }
}

// ---------------- K5: spatial-att fuse + final outputs ----------------
__global__ __launch_bounds__(256) void fuse_kernel(const float* __restrict__ RGB,
                                                   const float* __restrict__ T,
                                                   const float* __restrict__ coefs,
                                                   const float* __restrict__ srb,
                                                   const float* __restrict__ stb,
                                                   float* __restrict__ out) {
    int b = blockIdx.y;
    int t = threadIdx.x;
    int w = t >> 6, lane = t & 63;
    int pix = blockIdx.x * 256 + lane * 4;
    __shared__ float sco[4][128];
    for (int i = t; i < 512; i += 256) {
        int a = i >> 7, c = i & 127;
        sco[a][c] = coefs[a * 512 + b * 128 + c];
    }
    __syncthreads();
    const float* rp = RGB + (size_t)b * NC * HW;
    const float* tp = T + (size_t)b * NC * HW;
    // pass 1: f_r - f_t (each warp owns 32 channels)
    float4 df = make_float4(0.f, 0.f, 0.f, 0.f);
    for (int ci = 0; ci < 32; ++ci) {
        int c = w + ci * 4;
        size_t off = (size_t)c * HW + pix;
        float4 r = *(const float4*)(rp + off);
        float4 tv = *(const float4*)(tp + off);
        float wrc = sco[2][c], wtc = sco[3][c];
        df.x += r.x * wrc - tv.x * wtc;
        df.y += r.y * wrc - tv.y * wtc;
        df.z += r.z * wrc - tv.z * wtc;
        df.w += r.w * wrc - tv.w * wtc;
    }
    __shared__ float4 sdf[4][64];
    sdf[w][lane] = df;
    __syncthreads();
    float4 d0 = sdf[0][lane], d1 = sdf[1][lane], d2 = sdf[2][lane], d3 = sdf[3][lane];
    float bias = srb[0] - stb[0];
    float ax = sigmoidf_(d0.x + d1.x + d2.x + d3.x + bias);
    float ay = sigmoidf_(d0.y + d1.y + d2.y + d3.y + bias);
    float az = sigmoidf_(d0.z + d1.z + d2.z + d3.z + bias);
    float aw = sigmoidf_(d0.w + d1.w + d2.w + d3.w + bias);
    // pass 2: scale and write both outputs
    float* outR = out + (size_t)b * NC * HW;
    float* outT = out + (size_t)NB * NC * HW + (size_t)b * NC * HW;
    for (int ci = 0; ci < 32; ++ci) {
        int c = w + ci * 4;
        size_t off = (size_t)c * HW + pix;
        float4 r = *(const float4*)(rp + off);
        float4 tv = *(const float4*)(tp + off);
        float arc = sco[0][c], atc = sco[1][c];
        float4 o1, o2;
        o1.x = r.x * arc * ax;  o2.x = tv.x * atc * (1.f - ax);
        o1.y = r.y * arc * ay;  o2.y = tv.y * atc * (1.f - ay);
        o1.z = r.z * arc * az;  o2.z = tv.z * atc * (1.f - az);
        o1.w = r.w * arc * aw;  o2.w = tv.w * atc * (1.f - aw);
        *(float4*)(outR + off) = o1;
        *(float4*)(outT + off) = o2;
    }
}

extern "C" void kernel_launch(void* const* d_in, const int* in_sizes, int n_in,
                              void* d_out, int out_size, void* d_ws, size_t ws_size,
                              hipStream_t stream) {
    const float* RGB       = (const float*)d_in[0];
    const float* T         = (const float*)d_in[1];
    const float* fp_down_w = (const float*)d_in[2];
    const float* fp_down_b = (const float*)d_in[3];
    const float* fp_up_w   = (const float*)d_in[4];
    const float* fp_up_b   = (const float*)d_in[5];
    const float* dw_w      = (const float*)d_in[6];
    const float* dw_b      = (const float*)d_in[7];
    const float* ca_down_w = (const float*)d_in[8];
    const float* ca_down_b = (const float*)d_in[9];
    const float* ca_up_w   = (const float*)d_in[10];
    const float* ca_up_b   = (const float*)d_in[11];
    const float* sr_w      = (const float*)d_in[12];
    const float* sr_b      = (const float*)d_in[13];
    const float* st_w      = (const float*)d_in[14];
    const float* st_b      = (const float*)d_in[15];
    float* out = (float*)d_out;
    float* ws  = (float*)d_ws;

    // ws float layout:
    //   [0,1024)      means (tau*512 + b*128 + c)
    //   [1024,2048)   ynorm (normalized feature-pool outputs)
    //   [2048,7168)   conv partial maxes: ((b*128+g)*5+yt)*2 + oc
    //   [7168,9216)   coefs: alpha_r | alpha_t | wr | wt   (each 512)
    mean_kernel<<<1024, 256, 0, stream>>>(RGB, T, ws);
    mlp_kernel<<<8, 256, 0, stream>>>(ws, fp_down_w, fp_down_b, fp_up_w, fp_up_b, ws + 1024);
    conv_max_kernel<<<dim3(5, 128, 4), 256, 0, stream>>>(RGB, T, dw_w, ws + 1024, ws + 2048);
    att_kernel<<<1, 256, 0, stream>>>(ws + 1024, ws + 2048, dw_b, ca_down_w, ca_down_b,
                                      ca_up_w, ca_up_b, sr_w, st_w, ws + 7168);
    fuse_kernel<<<dim3(100, 4), 256, 0, stream>>>(RGB, T, ws + 7168, sr_b, st_b, out);
}

// Round 2
// 194.439 us; speedup vs baseline: 1.1742x; 1.1742x over previous
//
#include <hip/hip_runtime.h>
#include <cfloat>
#include <cmath>

#define HW 25600      // 160*160
#define WIDTH 160
#define NB 4
#define NC 128

__device__ __forceinline__ float gelu_exact(float x) {
    return 0.5f * x * (1.f + erff(x * 0.70710678118654752f));
}
__device__ __forceinline__ float sigmoidf_(float x) {
    return 1.f / (1.f + expf(-x));
}

// ---------------- K1: per-plane means (tau*512 + b*128 + c) ----------------
__global__ __launch_bounds__(256) void mean_kernel(const float* __restrict__ RGB,
                                                   const float* __restrict__ T,
                                                   float* __restrict__ means) {
    int p = blockIdx.x;  // 0..1023
    const float* src = (p < 512) ? (RGB + (size_t)p * HW)
                                 : (T + (size_t)(p - 512) * HW);
    const float4* s4 = (const float4*)src;
    float s = 0.f;
    for (int i = threadIdx.x; i < HW / 4; i += 256) {
        float4 v = s4[i];
        s += (v.x + v.y) + (v.z + v.w);
    }
    for (int off = 32; off; off >>= 1) s += __shfl_down(s, off);
    __shared__ float r[4];
    if ((threadIdx.x & 63) == 0) r[threadIdx.x >> 6] = s;
    __syncthreads();
    if (threadIdx.x == 0) means[p] = (r[0] + r[1] + r[2] + r[3]) * (1.f / (float)HW);
}

// ---------------- K2: feature-pool MLP + L2-normalize, per (tau,b) ----------------
__global__ __launch_bounds__(256) void mlp_kernel(const float* __restrict__ means,
                                                  const float* __restrict__ dww,
                                                  const float* __restrict__ dwb,
                                                  const float* __restrict__ uww,
                                                  const float* __restrict__ uwb,
                                                  float* __restrict__ ynorm) {
    int tb = blockIdx.x;  // tau*4 + b
    int t = threadIdx.x;
    __shared__ float sm[128];
    __shared__ float sh[256];
    __shared__ float zz[256];
    __shared__ float r4[4];
    if (t < 128) sm[t] = means[tb * 128 + t];
    __syncthreads();
    float a = dwb[t];
    const float* wrow = dww + t * 128;
    for (int c = 0; c < 128; ++c) a += wrow[c] * sm[c];
    sh[t] = gelu_exact(a);
    __syncthreads();
    int c = t & 127, half = t >> 7;
    float z = 0.f;
    const float* urow = uww + c * 256 + half * 128;
    const float* hh = sh + half * 128;
    for (int j = 0; j < 128; ++j) z += urow[j] * hh[j];
    zz[t] = z;
    __syncthreads();
    float y = 0.f;
    if (t < 128) y = zz[t] + zz[t + 128] + uwb[t];
    float p = y * y;
    for (int off = 32; off; off >>= 1) p += __shfl_down(p, off);
    if ((t & 63) == 0) r4[t >> 6] = p;
    __syncthreads();
    float nrm = sqrtf(r4[0] + r4[1] + r4[2] + r4[3]);
    if (t < 128) ynorm[tb * 128 + t] = y / nrm;
}

// ---------------- K3: gated grouped 7x7 conv + spatial max (never materialized) ----------------
// 16 output rows per block (10 y-tiles). Per thread: 2 oc x 2 oy x 5 ox = 20 accs.
// Live regs ~ 20 acc + 22 win + 28 w  -> fits under 128-VGPR cap.
#define TW 166
#define TH 22
#define NYT 10
__global__ __launch_bounds__(256, 4) void conv_max_kernel(const float* __restrict__ RGB,
                                                          const float* __restrict__ T,
                                                          const float* __restrict__ dww,
                                                          const float* __restrict__ ynorm,
                                                          float* __restrict__ part) {
    int yt = blockIdx.x;  // 0..9
    int g  = blockIdx.y;  // 0..127
    int b  = blockIdx.z;  // 0..3
    int t  = threadIdx.x;
    __shared__ float tile[2 * TH * TW];   // 29.2 KB
    __shared__ float wsm[196];
    __shared__ float r0s[4], r1s[4];
    for (int i = t; i < 196; i += 256) wsm[i] = dww[g * 196 + i];
    int ic0 = 2 * g;
    int c0 = ic0 & 127, c1 = (ic0 + 1) & 127;
    const float* base = (ic0 < 128) ? RGB : T;
    const float* plane0 = base + ((size_t)(b * 128 + c0)) * HW;
    const float* plane1 = base + ((size_t)(b * 128 + c1)) * HW;
    int i0 = b * 128 + c0, i1 = b * 128 + c1;
    int j0 = i0 & 3, k0 = i0 >> 2, j1 = i1 & 3, k1 = i1 >> 2;
    float gate0 = sigmoidf_(128.f * ynorm[j0 * 128 + j0] * ynorm[512 + j0 * 128 + k0]);
    float gate1 = sigmoidf_(128.f * ynorm[j1 * 128 + j1] * ynorm[512 + j1 * 128 + k1]);
    int y0 = yt * 16 - 3;
    for (int i = t; i < 2 * TH * TW; i += 256) {
        int chl = i / (TH * TW);
        int rem = i - chl * (TH * TW);
        int row = rem / TW;
        int col = rem - row * TW;
        int gy = y0 + row, gx = col - 3;
        float v = 0.f;
        if (gy >= 0 && gy < 160 && gx >= 0 && gx < 160) {
            const float* pl = chl ? plane1 : plane0;
            float gt = chl ? gate1 : gate0;
            v = pl[gy * WIDTH + gx] * gt;
        }
        tile[i] = v;
    }
    __syncthreads();
    int xs = (t & 31) * 5;
    int ys = (t >> 5) * 2;
    float acc[2][2][5];
    #pragma unroll
    for (int o = 0; o < 2; ++o)
        #pragma unroll
        for (int i = 0; i < 2; ++i)
            #pragma unroll
            for (int j = 0; j < 5; ++j) acc[o][i][j] = 0.f;
    #pragma unroll
    for (int ky = 0; ky < 7; ++ky) {
        float w00[7], w01[7], w10[7], w11[7];  // [oc][ic]
        #pragma unroll
        for (int kx = 0; kx < 7; ++kx) {
            w00[kx] = wsm[ky * 7 + kx];
            w01[kx] = wsm[49 + ky * 7 + kx];
            w10[kx] = wsm[98 + ky * 7 + kx];
            w11[kx] = wsm[147 + ky * 7 + kx];
        }
        #pragma unroll
        for (int oy = 0; oy < 2; ++oy) {
            int row = ys + oy + ky;
            const float* t0 = tile + row * TW + xs;
            const float* t1 = tile + TH * TW + row * TW + xs;
            float win0[11], win1[11];
            #pragma unroll
            for (int j = 0; j < 11; ++j) { win0[j] = t0[j]; win1[j] = t1[j]; }
            #pragma unroll
            for (int kx = 0; kx < 7; ++kx) {
                #pragma unroll
                for (int ox = 0; ox < 5; ++ox) {
                    acc[0][oy][ox] = fmaf(w00[kx], win0[ox + kx], acc[0][oy][ox]);
                    acc[0][oy][ox] = fmaf(w01[kx], win1[ox + kx], acc[0][oy][ox]);
                    acc[1][oy][ox] = fmaf(w10[kx], win0[ox + kx], acc[1][oy][ox]);
                    acc[1][oy][ox] = fmaf(w11[kx], win1[ox + kx], acc[1][oy][ox]);
                }
            }
        }
    }
    float m0 = -FLT_MAX, m1 = -FLT_MAX;
    #pragma unroll
    for (int i = 0; i < 2; ++i)
        #pragma unroll
        for (int j = 0; j < 5; ++j) {
            m0 = fmaxf(m0, fmaxf(acc[0][i][j], acc[0][i][j]));
            m1 = fmaxf(m1, acc[1][i][j]);
            m0 = fmaxf(m0, acc[0][i][j]);
        }
    for (int off = 32; off; off >>= 1) {
        m0 = fmaxf(m0, __shfl_down(m0, off));
        m1 = fmaxf(m1, __shfl_down(m1, off));
    }
    if ((t & 63) == 0) { r0s[t >> 6] = m0; r1s[t >> 6] = m1; }
    __syncthreads();
    if (t == 0) {
        m0 = fmaxf(fmaxf(r0s[0], r0s[1]), fmaxf(r0s[2], r0s[3]));
        m1 = fmaxf(fmaxf(r1s[0], r1s[1]), fmaxf(r1s[2], r1s[3]));
        int bb = ((b * 128 + g) * NYT + yt) * 2;
        part[bb] = m0;
        part[bb + 1] = m1;
    }
}

// ---------------- K4: max-reduce + channel-att MLP -> per-channel coefficients ----------------
__global__ __launch_bounds__(256) void att_kernel(const float* __restrict__ ynorm,
                                                  const float* __restrict__ part,
                                                  const float* __restrict__ dwb,
                                                  const float* __restrict__ cdw,
                                                  const float* __restrict__ cdb,
                                                  const float* __restrict__ cuw,
                                                  const float* __restrict__ cub,
                                                  const float* __restrict__ srw,
                                                  const float* __restrict__ stw,
                                                  float* __restrict__ coefs) {
    int t = threadIdx.x;
    __shared__ float scg[512];
    __shared__ float smax[1024];
    __shared__ float sh2[64];
    __shared__ float sfg[1024];
    for (int idx = t; idx < 512; idx += 256) {
        int kk = idx >> 2, j = idx & 3;
        scg[idx] = sigmoidf_(128.f * ynorm[j * 128 + j] * ynorm[512 + j * 128 + kk]);
    }
    for (int idx = t; idx < 1024; idx += 256) {
        int b = idx >> 8, o = idx & 255;
        int gg = o >> 1, oc = o & 1;
        const float* pp = part + ((b * 128 + gg) * NYT) * 2 + oc;
        float m = pp[0];
        #pragma unroll
        for (int yt = 1; yt < NYT; ++yt) m = fmaxf(m, pp[yt * 2]);
        smax[idx] = m + dwb[o];
    }
    __syncthreads();
    if (t < 64) {
        int b = t >> 4, j = t & 15;
        float a = cdb[j];
        const float* wrow = cdw + j * 256;
        const float* mx = smax + b * 256;
        for (int o = 0; o < 256; ++o) a += wrow[o] * mx[o];
        sh2[t] = gelu_exact(a);
    }
    __syncthreads();
    for (int idx = t; idx < 1024; idx += 256) {
        int b = idx >> 8, o = idx & 255;
        float z = cub[o];
        const float* ur = cuw + o * 16;
        const float* hh = sh2 + b * 16;
        #pragma unroll
        for (int j = 0; j < 16; ++j) z += ur[j] * hh[j];
        sfg[idx] = sigmoidf_(z);
    }
    __syncthreads();
    for (int idx = t; idx < 512; idx += 256) {
        int b = idx >> 7, c = idx & 127;
        float cgv = scg[idx];
        float ar = cgv * sfg[b * 256 + c] + 1.f - cgv;
        float at = cgv * sfg[b * 256 + 128 + c] + 1.f - cgv;
        coefs[idx] = ar;
        coefs[512 + idx] = at;
        coefs[1024 + idx] = ar * srw[c];
        coefs[1536 + idx] = at * stw[c];
    }
}

// ---------------- K5: spatial-att fuse + final outputs ----------------
__global__ __launch_bounds__(256) void fuse_kernel(const float* __restrict__ RGB,
                                                   const float* __restrict__ T,
                                                   const float* __restrict__ coefs,
                                                   const float* __restrict__ srb,
                                                   const float* __restrict__ stb,
                                                   float* __restrict__ out) {
    int b = blockIdx.y;
    int t = threadIdx.x;
    int w = t >> 6, lane = t & 63;
    int pix = blockIdx.x * 256 + lane * 4;
    __shared__ float sco[4][128];
    for (int i = t; i < 512; i += 256) {
        int a = i >> 7, c = i & 127;
        sco[a][c] = coefs[a * 512 + b * 128 + c];
    }
    __syncthreads();
    const float* rp = RGB + (size_t)b * NC * HW;
    const float* tp = T + (size_t)b * NC * HW;
    float4 df = make_float4(0.f, 0.f, 0.f, 0.f);
    for (int ci = 0; ci < 32; ++ci) {
        int c = w + ci * 4;
        size_t off = (size_t)c * HW + pix;
        float4 r = *(const float4*)(rp + off);
        float4 tv = *(const float4*)(tp + off);
        float wrc = sco[2][c], wtc = sco[3][c];
        df.x += r.x * wrc - tv.x * wtc;
        df.y += r.y * wrc - tv.y * wtc;
        df.z += r.z * wrc - tv.z * wtc;
        df.w += r.w * wrc - tv.w * wtc;
    }
    __shared__ float4 sdf[4][64];
    sdf[w][lane] = df;
    __syncthreads();
    float4 d0 = sdf[0][lane], d1 = sdf[1][lane], d2 = sdf[2][lane], d3 = sdf[3][lane];
    float bias = srb[0] - stb[0];
    float ax = sigmoidf_(d0.x + d1.x + d2.x + d3.x + bias);
    float ay = sigmoidf_(d0.y + d1.y + d2.y + d3.y + bias);
    float az = sigmoidf_(d0.z + d1.z + d2.z + d3.z + bias);
    float aw = sigmoidf_(d0.w + d1.w + d2.w + d3.w + bias);
    float* outR = out + (size_t)b * NC * HW;
    float* outT = out + (size_t)NB * NC * HW + (size_t)b * NC * HW;
    for (int ci = 0; ci < 32; ++ci) {
        int c = w + ci * 4;
        size_t off = (size_t)c * HW + pix;
        float4 r = *(const float4*)(rp + off);
        float4 tv = *(const float4*)(tp + off);
        float arc = sco[0][c], atc = sco[1][c];
        float4 o1, o2;
        o1.x = r.x * arc * ax;  o2.x = tv.x * atc * (1.f - ax);
        o1.y = r.y * arc * ay;  o2.y = tv.y * atc * (1.f - ay);
        o1.z = r.z * arc * az;  o2.z = tv.z * atc * (1.f - az);
        o1.w = r.w * arc * aw;  o2.w = tv.w * atc * (1.f - aw);
        *(float4*)(outR + off) = o1;
        *(float4*)(outT + off) = o2;
    }
}

extern "C" void kernel_launch(void* const* d_in, const int* in_sizes, int n_in,
                              void* d_out, int out_size, void* d_ws, size_t ws_size,
                              hipStream_t stream) {
    const float* RGB       = (const float*)d_in[0];
    const float* T         = (const float*)d_in[1];
    const float* fp_down_w = (const float*)d_in[2];
    const float* fp_down_b = (const float*)d_in[3];
    const float* fp_up_w   = (const float*)d_in[4];
    const float* fp_up_b   = (const float*)d_in[5];
    const float* dw_w      = (const float*)d_in[6];
    const float* dw_b      = (const float*)d_in[7];
    const float* ca_down_w = (const float*)d_in[8];
    const float* ca_down_b = (const float*)d_in[9];
    const float* ca_up_w   = (const float*)d_in[10];
    const float* ca_up_b   = (const float*)d_in[11];
    const float* sr_w      = (const float*)d_in[12];
    const float* sr_b      = (const float*)d_in[13];
    const float* st_w      = (const float*)d_in[14];
    const float* st_b      = (const float*)d_in[15];
    float* out = (float*)d_out;
    float* ws  = (float*)d_ws;

    // ws float layout:
    //   [0,1024)        means (tau*512 + b*128 + c)
    //   [1024,2048)     ynorm
    //   [2048,12288)    conv partial maxes: ((b*128+g)*10+yt)*2 + oc
    //   [12288,14336)   coefs: alpha_r | alpha_t | wr | wt  (each 512)
    mean_kernel<<<1024, 256, 0, stream>>>(RGB, T, ws);
    mlp_kernel<<<8, 256, 0, stream>>>(ws, fp_down_w, fp_down_b, fp_up_w, fp_up_b, ws + 1024);
    conv_max_kernel<<<dim3(NYT, 128, 4), 256, 0, stream>>>(RGB, T, dw_w, ws + 1024, ws + 2048);
    att_kernel<<<1, 256, 0, stream>>>(ws + 1024, ws + 2048, dw_b, ca_down_w, ca_down_b,
                                      ca_up_w, ca_up_b, sr_w, st_w, ws + 12288);
    fuse_kernel<<<dim3(100, 4), 256, 0, stream>>>(RGB, T, ws + 12288, sr_b, st_b, out);
}

// Round 4
// 162.234 us; speedup vs baseline: 1.4073x; 1.1985x over previous
//
#include <hip/hip_runtime.h>
#include <cfloat>
#include <cmath>

#define HW 25600      // 160*160
#define WIDTH 160
#define NB 4
#define NC 128

typedef _Float16 half2v __attribute__((ext_vector_type(2)));

__device__ __forceinline__ float gelu_exact(float x) {
    return 0.5f * x * (1.f + erff(x * 0.70710678118654752f));
}
__device__ __forceinline__ float sigmoidf_(float x) {
    return 1.f / (1.f + expf(-x));
}

#if __has_builtin(__builtin_amdgcn_fdot2)
__device__ __forceinline__ float fdot2_(half2v a, half2v b, float c) {
    return __builtin_amdgcn_fdot2(a, b, c, false);
}
#else
__device__ __forceinline__ float fdot2_(half2v a, half2v b, float c) {
    return c + (float)a[0] * (float)b[0] + (float)a[1] * (float)b[1];
}
#endif

__device__ __forceinline__ unsigned pack_pkrtz(float a, float b) {
    return __builtin_bit_cast(unsigned, __builtin_amdgcn_cvt_pkrtz(a, b));
}
__device__ __forceinline__ half2v unpack_h2(unsigned u) {
    return __builtin_bit_cast(half2v, u);
}

// ---------------- K0: pack conv weights -> f16x2 (ic0,ic1), layout [g][ky][oc][kx] ----------------
__global__ __launch_bounds__(256) void pack_w_kernel(const float* __restrict__ dww,
                                                     unsigned* __restrict__ wpk) {
    int i = blockIdx.x * 256 + threadIdx.x;  // 128*98 = 12544
    if (i >= 128 * 98) return;
    int g = i / 98; int r = i - g * 98;
    int ky = r / 14; int r2 = r - ky * 14;
    int oc = r2 / 7; int kx = r2 - oc * 7;
    int o = 2 * g + oc;
    float wa = dww[(o * 2 + 0) * 49 + ky * 7 + kx];
    float wb = dww[(o * 2 + 1) * 49 + ky * 7 + kx];
    wpk[i] = pack_pkrtz(wa, wb);
}

// ---------------- K1: per-plane means (tau*512 + b*128 + c) ----------------
__global__ __launch_bounds__(256) void mean_kernel(const float* __restrict__ RGB,
                                                   const float* __restrict__ T,
                                                   float* __restrict__ means) {
    int p = blockIdx.x;  // 0..1023
    const float* src = (p < 512) ? (RGB + (size_t)p * HW)
                                 : (T + (size_t)(p - 512) * HW);
    const float4* s4 = (const float4*)src;
    float s = 0.f;
    for (int i = threadIdx.x; i < HW / 4; i += 256) {
        float4 v = s4[i];
        s += (v.x + v.y) + (v.z + v.w);
    }
    for (int off = 32; off; off >>= 1) s += __shfl_down(s, off);
    __shared__ float r[4];
    if ((threadIdx.x & 63) == 0) r[threadIdx.x >> 6] = s;
    __syncthreads();
    if (threadIdx.x == 0) means[p] = (r[0] + r[1] + r[2] + r[3]) * (1.f / (float)HW);
}

// ---------------- K2: feature-pool MLP + L2-normalize, per (tau,b) ----------------
__global__ __launch_bounds__(256) void mlp_kernel(const float* __restrict__ means,
                                                  const float* __restrict__ dww,
                                                  const float* __restrict__ dwb,
                                                  const float* __restrict__ uww,
                                                  const float* __restrict__ uwb,
                                                  float* __restrict__ ynorm) {
    int tb = blockIdx.x;  // tau*4 + b
    int t = threadIdx.x;
    __shared__ float sm[128];
    __shared__ float sh[256];
    __shared__ float zz[256];
    __shared__ float r4[4];
    if (t < 128) sm[t] = means[tb * 128 + t];
    __syncthreads();
    float a = dwb[t];
    const float* wrow = dww + t * 128;
    for (int c = 0; c < 128; ++c) a += wrow[c] * sm[c];
    sh[t] = gelu_exact(a);
    __syncthreads();
    int c = t & 127, half = t >> 7;
    float z = 0.f;
    const float* urow = uww + c * 256 + half * 128;
    const float* hh = sh + half * 128;
    for (int j = 0; j < 128; ++j) z += urow[j] * hh[j];
    zz[t] = z;
    __syncthreads();
    float y = 0.f;
    if (t < 128) y = zz[t] + zz[t + 128] + uwb[t];
    float p = y * y;
    for (int off = 32; off; off >>= 1) p += __shfl_down(p, off);
    if ((t & 63) == 0) r4[t >> 6] = p;
    __syncthreads();
    float nrm = sqrtf(r4[0] + r4[1] + r4[2] + r4[3]);
    if (t < 128) ynorm[tb * 128 + t] = y / nrm;
}

// ---------------- K3: gated grouped 7x7 conv + spatial max, f16x2 dot2 ----------------
// Tile: 22 rows x 166 cols of (ch0,ch1) f16x2 = 14.6 KB. Per thread: 1 oy x 10 ox x 2 oc.
// Weights via block-uniform loads of pre-packed wpk -> SGPRs.
#define TW2 166
#define THR 22
#define NYT 10
__global__ __launch_bounds__(256, 4) void conv_max_kernel(const float* __restrict__ RGB,
                                                          const float* __restrict__ T,
                                                          const unsigned* __restrict__ wpk,
                                                          const float* __restrict__ ynorm,
                                                          float* __restrict__ part) {
    int yt = blockIdx.x;  // 0..9
    int g  = blockIdx.y;  // 0..127
    int b  = blockIdx.z;  // 0..3
    int t  = threadIdx.x;
    __shared__ unsigned tile[THR * TW2];   // 14.6 KB
    __shared__ float r0s[4], r1s[4];
    int ic0 = 2 * g;
    int c0 = ic0 & 127, c1 = (ic0 + 1) & 127;
    const float* base = (ic0 < 128) ? RGB : T;
    const float* plane0 = base + ((size_t)(b * 128 + c0)) * HW;
    const float* plane1 = base + ((size_t)(b * 128 + c1)) * HW;
    int i0 = b * 128 + c0, i1 = b * 128 + c1;
    int j0 = i0 & 3, k0 = i0 >> 2, j1 = i1 & 3, k1 = i1 >> 2;
    float gate0 = sigmoidf_(128.f * ynorm[j0 * 128 + j0] * ynorm[512 + j0 * 128 + k0]);
    float gate1 = sigmoidf_(128.f * ynorm[j1 * 128 + j1] * ynorm[512 + j1 * 128 + k1]);
    // stage gated, zero-padded, channel-interleaved f16 tile
    int y0 = yt * 16 - 3;
    for (int e = t; e < THR * TW2; e += 256) {
        int row = e / TW2;
        int col = e - row * TW2;
        int gy = y0 + row, gx = col - 3;
        float v0 = 0.f, v1 = 0.f;
        if (gy >= 0 && gy < 160 && gx >= 0 && gx < 160) {
            int off = gy * WIDTH + gx;
            v0 = plane0[off] * gate0;
            v1 = plane1[off] * gate1;
        }
        tile[e] = pack_pkrtz(v0, v1);
    }
    __syncthreads();
    int xs = (t & 15) * 10;
    int ys = t >> 4;        // 0..15
    float acc0[10], acc1[10];
    #pragma unroll
    for (int j = 0; j < 10; ++j) { acc0[j] = 0.f; acc1[j] = 0.f; }
    const unsigned* wgp = wpk + g * 98;   // block-uniform -> scalar loads
    #pragma unroll 1
    for (int ky = 0; ky < 7; ++ky) {
        unsigned wk[14];
        #pragma unroll
        for (int j = 0; j < 14; ++j) wk[j] = wgp[ky * 14 + j];
        const unsigned* trow = tile + (ys + ky) * TW2 + xs;
        unsigned win[16];
        #pragma unroll
        for (int j = 0; j < 16; ++j) win[j] = trow[j];
        #pragma unroll
        for (int kx = 0; kx < 7; ++kx) {
            half2v w0 = unpack_h2(wk[kx]);
            half2v w1 = unpack_h2(wk[7 + kx]);
            #pragma unroll
            for (int ox = 0; ox < 10; ++ox) {
                half2v wv = unpack_h2(win[ox + kx]);
                acc0[ox] = fdot2_(w0, wv, acc0[ox]);
                acc1[ox] = fdot2_(w1, wv, acc1[ox]);
            }
        }
    }
    float m0 = -FLT_MAX, m1 = -FLT_MAX;
    #pragma unroll
    for (int j = 0; j < 10; ++j) {
        m0 = fmaxf(m0, acc0[j]);
        m1 = fmaxf(m1, acc1[j]);
    }
    for (int off = 32; off; off >>= 1) {
        m0 = fmaxf(m0, __shfl_down(m0, off));
        m1 = fmaxf(m1, __shfl_down(m1, off));
    }
    if ((t & 63) == 0) { r0s[t >> 6] = m0; r1s[t >> 6] = m1; }
    __syncthreads();
    if (t == 0) {
        m0 = fmaxf(fmaxf(r0s[0], r0s[1]), fmaxf(r0s[2], r0s[3]));
        m1 = fmaxf(fmaxf(r1s[0], r1s[1]), fmaxf(r1s[2], r1s[3]));
        int bb = ((b * 128 + g) * NYT + yt) * 2;
        part[bb] = m0;
        part[bb + 1] = m1;
    }
}

// ---------------- K4: max-reduce + channel-att MLP -> per-channel coefficients ----------------
__global__ __launch_bounds__(256) void att_kernel(const float* __restrict__ ynorm,
                                                  const float* __restrict__ part,
                                                  const float* __restrict__ dwb,
                                                  const float* __restrict__ cdw,
                                                  const float* __restrict__ cdb,
                                                  const float* __restrict__ cuw,
                                                  const float* __restrict__ cub,
                                                  const float* __restrict__ srw,
                                                  const float* __restrict__ stw,
                                                  float* __restrict__ coefs) {
    int t = threadIdx.x;
    __shared__ float scg[512];
    __shared__ float smax[1024];
    __shared__ float sh2[64];
    __shared__ float sfg[1024];
    for (int idx = t; idx < 512; idx += 256) {
        int kk = idx >> 2, j = idx & 3;
        scg[idx] = sigmoidf_(128.f * ynorm[j * 128 + j] * ynorm[512 + j * 128 + kk]);
    }
    for (int idx = t; idx < 1024; idx += 256) {
        int b = idx >> 8, o = idx & 255;
        int gg = o >> 1, oc = o & 1;
        const float* pp = part + ((b * 128 + gg) * NYT) * 2 + oc;
        float m = pp[0];
        #pragma unroll
        for (int yt = 1; yt < NYT; ++yt) m = fmaxf(m, pp[yt * 2]);
        smax[idx] = m + dwb[o];
    }
    __syncthreads();
    if (t < 64) {
        int b = t >> 4, j = t & 15;
        float a = cdb[j];
        const float* wrow = cdw + j * 256;
        const float* mx = smax + b * 256;
        for (int o = 0; o < 256; ++o) a += wrow[o] * mx[o];
        sh2[t] = gelu_exact(a);
    }
    __syncthreads();
    for (int idx = t; idx < 1024; idx += 256) {
        int b = idx >> 8, o = idx & 255;
        float z = cub[o];
        const float* ur = cuw + o * 16;
        const float* hh = sh2 + b * 16;
        #pragma unroll
        for (int j = 0; j < 16; ++j) z += ur[j] * hh[j];
        sfg[idx] = sigmoidf_(z);
    }
    __syncthreads();
    for (int idx = t; idx < 512; idx += 256) {
        int b = idx >> 7, c = idx & 127;
        float cgv = scg[idx];
        float ar = cgv * sfg[b * 256 + c] + 1.f - cgv;
        float at = cgv * sfg[b * 256 + 128 + c] + 1.f - cgv;
        coefs[idx] = ar;
        coefs[512 + idx] = at;
        coefs[1024 + idx] = ar * srw[c];
        coefs[1536 + idx] = at * stw[c];
    }
}

// ---------------- K5: spatial-att fuse + final outputs ----------------
__global__ __launch_bounds__(256) void fuse_kernel(const float* __restrict__ RGB,
                                                   const float* __restrict__ T,
                                                   const float* __restrict__ coefs,
                                                   const float* __restrict__ srb,
                                                   const float* __restrict__ stb,
                                                   float* __restrict__ out) {
    int b = blockIdx.y;
    int t = threadIdx.x;
    int w = t >> 6, lane = t & 63;
    int pix = blockIdx.x * 256 + lane * 4;
    __shared__ float sco[4][128];
    for (int i = t; i < 512; i += 256) {
        int a = i >> 7, c = i & 127;
        sco[a][c] = coefs[a * 512 + b * 128 + c];
    }
    __syncthreads();
    const float* rp = RGB + (size_t)b * NC * HW;
    const float* tp = T + (size_t)b * NC * HW;
    float4 df = make_float4(0.f, 0.f, 0.f, 0.f);
    for (int ci = 0; ci < 32; ++ci) {
        int c = w + ci * 4;
        size_t off = (size_t)c * HW + pix;
        float4 r = *(const float4*)(rp + off);
        float4 tv = *(const float4*)(tp + off);
        float wrc = sco[2][c], wtc = sco[3][c];
        df.x += r.x * wrc - tv.x * wtc;
        df.y += r.y * wrc - tv.y * wtc;
        df.z += r.z * wrc - tv.z * wtc;
        df.w += r.w * wrc - tv.w * wtc;
    }
    __shared__ float4 sdf[4][64];
    sdf[w][lane] = df;
    __syncthreads();
    float4 d0 = sdf[0][lane], d1 = sdf[1][lane], d2 = sdf[2][lane], d3 = sdf[3][lane];
    float bias = srb[0] - stb[0];
    float ax = sigmoidf_(d0.x + d1.x + d2.x + d3.x + bias);
    float ay = sigmoidf_(d0.y + d1.y + d2.y + d3.y + bias);
    float az = sigmoidf_(d0.z + d1.z + d2.z + d3.z + bias);
    float aw = sigmoidf_(d0.w + d1.w + d2.w + d3.w + bias);
    float* outR = out + (size_t)b * NC * HW;
    float* outT = out + (size_t)NB * NC * HW + (size_t)b * NC * HW;
    for (int ci = 0; ci < 32; ++ci) {
        int c = w + ci * 4;
        size_t off = (size_t)c * HW + pix;
        float4 r = *(const float4*)(rp + off);
        float4 tv = *(const float4*)(tp + off);
        float arc = sco[0][c], atc = sco[1][c];
        float4 o1, o2;
        o1.x = r.x * arc * ax;  o2.x = tv.x * atc * (1.f - ax);
        o1.y = r.y * arc * ay;  o2.y = tv.y * atc * (1.f - ay);
        o1.z = r.z * arc * az;  o2.z = tv.z * atc * (1.f - az);
        o1.w = r.w * arc * aw;  o2.w = tv.w * atc * (1.f - aw);
        *(float4*)(outR + off) = o1;
        *(float4*)(outT + off) = o2;
    }
}

extern "C" void kernel_launch(void* const* d_in, const int* in_sizes, int n_in,
                              void* d_out, int out_size, void* d_ws, size_t ws_size,
                              hipStream_t stream) {
    const float* RGB       = (const float*)d_in[0];
    const float* T         = (const float*)d_in[1];
    const float* fp_down_w = (const float*)d_in[2];
    const float* fp_down_b = (const float*)d_in[3];
    const float* fp_up_w   = (const float*)d_in[4];
    const float* fp_up_b   = (const float*)d_in[5];
    const float* dw_w      = (const float*)d_in[6];
    const float* dw_b      = (const float*)d_in[7];
    const float* ca_down_w = (const float*)d_in[8];
    const float* ca_down_b = (const float*)d_in[9];
    const float* ca_up_w   = (const float*)d_in[10];
    const float* ca_up_b   = (const float*)d_in[11];
    const float* sr_w      = (const float*)d_in[12];
    const float* sr_b      = (const float*)d_in[13];
    const float* st_w      = (const float*)d_in[14];
    const float* st_b      = (const float*)d_in[15];
    float* out = (float*)d_out;
    float* ws  = (float*)d_ws;

    // ws float layout:
    //   [0,1024)        means (tau*512 + b*128 + c)
    //   [1024,2048)     ynorm
    //   [2048,12288)    conv partial maxes: ((b*128+g)*10+yt)*2 + oc
    //   [12288,14336)   coefs: alpha_r | alpha_t | wr | wt  (each 512)
    //   [14336,26880)   wpk: packed f16x2 conv weights [g][ky][oc][kx]
    unsigned* wpk = (unsigned*)(ws + 14336);
    pack_w_kernel<<<49, 256, 0, stream>>>(dw_w, wpk);
    mean_kernel<<<1024, 256, 0, stream>>>(RGB, T, ws);
    mlp_kernel<<<8, 256, 0, stream>>>(ws, fp_down_w, fp_down_b, fp_up_w, fp_up_b, ws + 1024);
    conv_max_kernel<<<dim3(NYT, 128, 4), 256, 0, stream>>>(RGB, T, wpk, ws + 1024, ws + 2048);
    att_kernel<<<1, 256, 0, stream>>>(ws + 1024, ws + 2048, dw_b, ca_down_w, ca_down_b,
                                      ca_up_w, ca_up_b, sr_w, st_w, ws + 12288);
    fuse_kernel<<<dim3(100, 4), 256, 0, stream>>>(RGB, T, ws + 12288, sr_b, st_b, out);
}

// Round 5
// 153.007 us; speedup vs baseline: 1.4921x; 1.0603x over previous
//
#include <hip/hip_runtime.h>
#include <cfloat>
#include <cmath>

#define HW 25600      // 160*160
#define WIDTH 160
#define NB 4
#define NC 128

typedef _Float16 half2v __attribute__((ext_vector_type(2)));
typedef float f32x4 __attribute__((ext_vector_type(4)));

__device__ __forceinline__ float gelu_exact(float x) {
    return 0.5f * x * (1.f + erff(x * 0.70710678118654752f));
}
__device__ __forceinline__ float sigmoidf_(float x) {
    return 1.f / (1.f + expf(-x));
}

#if __has_builtin(__builtin_amdgcn_fdot2)
__device__ __forceinline__ float fdot2_(half2v a, half2v b, float c) {
    return __builtin_amdgcn_fdot2(a, b, c, false);
}
#else
__device__ __forceinline__ float fdot2_(half2v a, half2v b, float c) {
    return c + (float)a[0] * (float)b[0] + (float)a[1] * (float)b[1];
}
#endif

__device__ __forceinline__ unsigned pack_pkrtz(float a, float b) {
    return __builtin_bit_cast(unsigned, __builtin_amdgcn_cvt_pkrtz(a, b));
}
__device__ __forceinline__ half2v unpack_h2(unsigned u) {
    return __builtin_bit_cast(half2v, u);
}

// ---------------- K0: pack conv weights -> f16x2 (ic0,ic1), layout [g][ky][oc][kx] ----------------
__global__ __launch_bounds__(256) void pack_w_kernel(const float* __restrict__ dww,
                                                     unsigned* __restrict__ wpk) {
    int i = blockIdx.x * 256 + threadIdx.x;  // 128*98 = 12544
    if (i >= 128 * 98) return;
    int g = i / 98; int r = i - g * 98;
    int ky = r / 14; int r2 = r - ky * 14;
    int oc = r2 / 7; int kx = r2 - oc * 7;
    int o = 2 * g + oc;
    float wa = dww[(o * 2 + 0) * 49 + ky * 7 + kx];
    float wb = dww[(o * 2 + 1) * 49 + ky * 7 + kx];
    wpk[i] = pack_pkrtz(wa, wb);
}

// ---------------- K1: per-plane means (tau*512 + b*128 + c) ----------------
__global__ __launch_bounds__(256) void mean_kernel(const float* __restrict__ RGB,
                                                   const float* __restrict__ T,
                                                   float* __restrict__ means) {
    int p = blockIdx.x;  // 0..1023
    const float* src = (p < 512) ? (RGB + (size_t)p * HW)
                                 : (T + (size_t)(p - 512) * HW);
    const float4* s4 = (const float4*)src;
    float s = 0.f;
    for (int i = threadIdx.x; i < HW / 4; i += 256) {
        float4 v = s4[i];
        s += (v.x + v.y) + (v.z + v.w);
    }
    for (int off = 32; off; off >>= 1) s += __shfl_down(s, off);
    __shared__ float r[4];
    if ((threadIdx.x & 63) == 0) r[threadIdx.x >> 6] = s;
    __syncthreads();
    if (threadIdx.x == 0) means[p] = (r[0] + r[1] + r[2] + r[3]) * (1.f / (float)HW);
}

// ---------------- K2: feature-pool MLP + L2-normalize, per (tau,b) ----------------
__global__ __launch_bounds__(256) void mlp_kernel(const float* __restrict__ means,
                                                  const float* __restrict__ dww,
                                                  const float* __restrict__ dwb,
                                                  const float* __restrict__ uww,
                                                  const float* __restrict__ uwb,
                                                  float* __restrict__ ynorm) {
    int tb = blockIdx.x;  // tau*4 + b
    int t = threadIdx.x;
    __shared__ float sm[128];
    __shared__ float sh[256];
    __shared__ float zz[256];
    __shared__ float r4[4];
    if (t < 128) sm[t] = means[tb * 128 + t];
    __syncthreads();
    float a = dwb[t];
    const float* wrow = dww + t * 128;
    for (int c = 0; c < 128; ++c) a += wrow[c] * sm[c];
    sh[t] = gelu_exact(a);
    __syncthreads();
    int c = t & 127, half = t >> 7;
    float z = 0.f;
    const float* urow = uww + c * 256 + half * 128;
    const float* hh = sh + half * 128;
    for (int j = 0; j < 128; ++j) z += urow[j] * hh[j];
    zz[t] = z;
    __syncthreads();
    float y = 0.f;
    if (t < 128) y = zz[t] + zz[t + 128] + uwb[t];
    float p = y * y;
    for (int off = 32; off; off >>= 1) p += __shfl_down(p, off);
    if ((t & 63) == 0) r4[t >> 6] = p;
    __syncthreads();
    float nrm = sqrtf(r4[0] + r4[1] + r4[2] + r4[3]);
    if (t < 128) ynorm[tb * 128 + t] = y / nrm;
}

// ---------------- K3: gated grouped 7x7 conv + spatial max, f16x2 dot2 ----------------
// Accumulators are NAMED SCALARS (R4 lesson: acc arrays live across the unroll-1
// ky loop got demoted to scratch -> VGPR_Count=20, 67us). Windows read as uint2.
#define TW2 166
#define THR 22
#define NYT 10
__global__ __launch_bounds__(256, 4) void conv_max_kernel(const float* __restrict__ RGB,
                                                          const float* __restrict__ T,
                                                          const unsigned* __restrict__ wpk,
                                                          const float* __restrict__ ynorm,
                                                          float* __restrict__ part) {
    int yt = blockIdx.x;  // 0..9
    int g  = blockIdx.y;  // 0..127
    int b  = blockIdx.z;  // 0..3
    int t  = threadIdx.x;
    __shared__ unsigned tile[THR * TW2];   // 14.6 KB
    __shared__ float r0s[4], r1s[4];
    int ic0 = 2 * g;
    int c0 = ic0 & 127, c1 = (ic0 + 1) & 127;
    const float* base = (ic0 < 128) ? RGB : T;
    const float* plane0 = base + ((size_t)(b * 128 + c0)) * HW;
    const float* plane1 = base + ((size_t)(b * 128 + c1)) * HW;
    int i0 = b * 128 + c0, i1 = b * 128 + c1;
    int j0 = i0 & 3, k0 = i0 >> 2, j1 = i1 & 3, k1 = i1 >> 2;
    float gate0 = sigmoidf_(128.f * ynorm[j0 * 128 + j0] * ynorm[512 + j0 * 128 + k0]);
    float gate1 = sigmoidf_(128.f * ynorm[j1 * 128 + j1] * ynorm[512 + j1 * 128 + k1]);
    int y0 = yt * 16 - 3;
    for (int e = t; e < THR * TW2; e += 256) {
        int row = e / TW2;
        int col = e - row * TW2;
        int gy = y0 + row, gx = col - 3;
        float v0 = 0.f, v1 = 0.f;
        if (gy >= 0 && gy < 160 && gx >= 0 && gx < 160) {
            int off = gy * WIDTH + gx;
            v0 = plane0[off] * gate0;
            v1 = plane1[off] * gate1;
        }
        tile[e] = pack_pkrtz(v0, v1);
    }
    __syncthreads();
    int xs = (t & 15) * 10;     // 40-byte aligned -> uint2 loads ok
    int ys = t >> 4;            // 0..15
    float a0 = 0.f, a1 = 0.f, a2 = 0.f, a3 = 0.f, a4 = 0.f;
    float a5 = 0.f, a6 = 0.f, a7 = 0.f, a8 = 0.f, a9 = 0.f;
    float b0 = 0.f, b1 = 0.f, b2 = 0.f, b3 = 0.f, b4 = 0.f;
    float b5 = 0.f, b6 = 0.f, b7 = 0.f, b8 = 0.f, b9 = 0.f;
    const unsigned* wgp = wpk + g * 98;   // block-uniform -> scalar loads
    #pragma unroll 1
    for (int ky = 0; ky < 7; ++ky) {
        unsigned wk[14];
        #pragma unroll
        for (int j = 0; j < 14; ++j) wk[j] = wgp[ky * 14 + j];
        const uint2* tr2 = (const uint2*)(tile + (ys + ky) * TW2 + xs);
        unsigned win[16];
        #pragma unroll
        for (int j = 0; j < 8; ++j) {
            uint2 p = tr2[j];
            win[2 * j] = p.x;
            win[2 * j + 1] = p.y;
        }
        #pragma unroll
        for (int kx = 0; kx < 7; ++kx) {
            half2v w0 = unpack_h2(wk[kx]);
            half2v w1 = unpack_h2(wk[7 + kx]);
            half2v v;
            v = unpack_h2(win[kx + 0]); a0 = fdot2_(w0, v, a0); b0 = fdot2_(w1, v, b0);
            v = unpack_h2(win[kx + 1]); a1 = fdot2_(w0, v, a1); b1 = fdot2_(w1, v, b1);
            v = unpack_h2(win[kx + 2]); a2 = fdot2_(w0, v, a2); b2 = fdot2_(w1, v, b2);
            v = unpack_h2(win[kx + 3]); a3 = fdot2_(w0, v, a3); b3 = fdot2_(w1, v, b3);
            v = unpack_h2(win[kx + 4]); a4 = fdot2_(w0, v, a4); b4 = fdot2_(w1, v, b4);
            v = unpack_h2(win[kx + 5]); a5 = fdot2_(w0, v, a5); b5 = fdot2_(w1, v, b5);
            v = unpack_h2(win[kx + 6]); a6 = fdot2_(w0, v, a6); b6 = fdot2_(w1, v, b6);
            v = unpack_h2(win[kx + 7]); a7 = fdot2_(w0, v, a7); b7 = fdot2_(w1, v, b7);
            v = unpack_h2(win[kx + 8]); a8 = fdot2_(w0, v, a8); b8 = fdot2_(w1, v, b8);
            v = unpack_h2(win[kx + 9]); a9 = fdot2_(w0, v, a9); b9 = fdot2_(w1, v, b9);
        }
    }
    float m0 = fmaxf(fmaxf(fmaxf(a0, a1), fmaxf(a2, a3)),
                     fmaxf(fmaxf(a4, a5), fmaxf(fmaxf(a6, a7), fmaxf(a8, a9))));
    float m1 = fmaxf(fmaxf(fmaxf(b0, b1), fmaxf(b2, b3)),
                     fmaxf(fmaxf(b4, b5), fmaxf(fmaxf(b6, b7), fmaxf(b8, b9))));
    for (int off = 32; off; off >>= 1) {
        m0 = fmaxf(m0, __shfl_down(m0, off));
        m1 = fmaxf(m1, __shfl_down(m1, off));
    }
    if ((t & 63) == 0) { r0s[t >> 6] = m0; r1s[t >> 6] = m1; }
    __syncthreads();
    if (t == 0) {
        m0 = fmaxf(fmaxf(r0s[0], r0s[1]), fmaxf(r0s[2], r0s[3]));
        m1 = fmaxf(fmaxf(r1s[0], r1s[1]), fmaxf(r1s[2], r1s[3]));
        int bb = ((b * 128 + g) * NYT + yt) * 2;
        part[bb] = m0;
        part[bb + 1] = m1;
    }
}

// ---------------- K4: max-reduce + channel-att MLP -> per-channel coefficients ----------------
__global__ __launch_bounds__(256) void att_kernel(const float* __restrict__ ynorm,
                                                  const float* __restrict__ part,
                                                  const float* __restrict__ dwb,
                                                  const float* __restrict__ cdw,
                                                  const float* __restrict__ cdb,
                                                  const float* __restrict__ cuw,
                                                  const float* __restrict__ cub,
                                                  const float* __restrict__ srw,
                                                  const float* __restrict__ stw,
                                                  float* __restrict__ coefs) {
    int t = threadIdx.x;
    __shared__ float scg[512];
    __shared__ float smax[1024];
    __shared__ float sh2[64];
    __shared__ float sfg[1024];
    for (int idx = t; idx < 512; idx += 256) {
        int kk = idx >> 2, j = idx & 3;
        scg[idx] = sigmoidf_(128.f * ynorm[j * 128 + j] * ynorm[512 + j * 128 + kk]);
    }
    for (int idx = t; idx < 1024; idx += 256) {
        int b = idx >> 8, o = idx & 255;
        int gg = o >> 1, oc = o & 1;
        const float* pp = part + ((b * 128 + gg) * NYT) * 2 + oc;
        float m = pp[0];
        #pragma unroll
        for (int yt = 1; yt < NYT; ++yt) m = fmaxf(m, pp[yt * 2]);
        smax[idx] = m + dwb[o];
    }
    __syncthreads();
    if (t < 64) {
        int b = t >> 4, j = t & 15;
        float a = cdb[j];
        const float* wrow = cdw + j * 256;
        const float* mx = smax + b * 256;
        for (int o = 0; o < 256; ++o) a += wrow[o] * mx[o];
        sh2[t] = gelu_exact(a);
    }
    __syncthreads();
    for (int idx = t; idx < 1024; idx += 256) {
        int b = idx >> 8, o = idx & 255;
        float z = cub[o];
        const float* ur = cuw + o * 16;
        const float* hh = sh2 + b * 16;
        #pragma unroll
        for (int j = 0; j < 16; ++j) z += ur[j] * hh[j];
        sfg[idx] = sigmoidf_(z);
    }
    __syncthreads();
    for (int idx = t; idx < 512; idx += 256) {
        int b = idx >> 7, c = idx & 127;
        float cgv = scg[idx];
        float ar = cgv * sfg[b * 256 + c] + 1.f - cgv;
        float at = cgv * sfg[b * 256 + 128 + c] + 1.f - cgv;
        coefs[idx] = ar;
        coefs[512 + idx] = at;
        coefs[1024 + idx] = ar * srw[c];
        coefs[1536 + idx] = at * stw[c];
    }
}

// ---------------- K5: spatial-att fuse + final outputs (NT stores) ----------------
__global__ __launch_bounds__(256) void fuse_kernel(const float* __restrict__ RGB,
                                                   const float* __restrict__ T,
                                                   const float* __restrict__ coefs,
                                                   const float* __restrict__ srb,
                                                   const float* __restrict__ stb,
                                                   float* __restrict__ out) {
    int b = blockIdx.y;
    int t = threadIdx.x;
    int w = t >> 6, lane = t & 63;
    int pix = blockIdx.x * 256 + lane * 4;
    __shared__ float sco[4][128];
    for (int i = t; i < 512; i += 256) {
        int a = i >> 7, c = i & 127;
        sco[a][c] = coefs[a * 512 + b * 128 + c];
    }
    __syncthreads();
    const float* rp = RGB + (size_t)b * NC * HW;
    const float* tp = T + (size_t)b * NC * HW;
    float4 df = make_float4(0.f, 0.f, 0.f, 0.f);
    for (int ci = 0; ci < 32; ++ci) {
        int c = w + ci * 4;
        size_t off = (size_t)c * HW + pix;
        float4 r = *(const float4*)(rp + off);
        float4 tv = *(const float4*)(tp + off);
        float wrc = sco[2][c], wtc = sco[3][c];
        df.x += r.x * wrc - tv.x * wtc;
        df.y += r.y * wrc - tv.y * wtc;
        df.z += r.z * wrc - tv.z * wtc;
        df.w += r.w * wrc - tv.w * wtc;
    }
    __shared__ float4 sdf[4][64];
    sdf[w][lane] = df;
    __syncthreads();
    float4 d0 = sdf[0][lane], d1 = sdf[1][lane], d2 = sdf[2][lane], d3 = sdf[3][lane];
    float bias = srb[0] - stb[0];
    float ax = sigmoidf_(d0.x + d1.x + d2.x + d3.x + bias);
    float ay = sigmoidf_(d0.y + d1.y + d2.y + d3.y + bias);
    float az = sigmoidf_(d0.z + d1.z + d2.z + d3.z + bias);
    float aw = sigmoidf_(d0.w + d1.w + d2.w + d3.w + bias);
    float* outR = out + (size_t)b * NC * HW;
    float* outT = out + (size_t)NB * NC * HW + (size_t)b * NC * HW;
    for (int ci = 0; ci < 32; ++ci) {
        int c = w + ci * 4;
        size_t off = (size_t)c * HW + pix;
        float4 r = *(const float4*)(rp + off);
        float4 tv = *(const float4*)(tp + off);
        float arc = sco[0][c], atc = sco[1][c];
        f32x4 o1, o2;
        o1.x = r.x * arc * ax;  o2.x = tv.x * atc * (1.f - ax);
        o1.y = r.y * arc * ay;  o2.y = tv.y * atc * (1.f - ay);
        o1.z = r.z * arc * az;  o2.z = tv.z * atc * (1.f - az);
        o1.w = r.w * arc * aw;  o2.w = tv.w * atc * (1.f - aw);
        __builtin_nontemporal_store(o1, (f32x4*)(outR + off));
        __builtin_nontemporal_store(o2, (f32x4*)(outT + off));
    }
}

extern "C" void kernel_launch(void* const* d_in, const int* in_sizes, int n_in,
                              void* d_out, int out_size, void* d_ws, size_t ws_size,
                              hipStream_t stream) {
    const float* RGB       = (const float*)d_in[0];
    const float* T         = (const float*)d_in[1];
    const float* fp_down_w = (const float*)d_in[2];
    const float* fp_down_b = (const float*)d_in[3];
    const float* fp_up_w   = (const float*)d_in[4];
    const float* fp_up_b   = (const float*)d_in[5];
    const float* dw_w      = (const float*)d_in[6];
    const float* dw_b      = (const float*)d_in[7];
    const float* ca_down_w = (const float*)d_in[8];
    const float* ca_down_b = (const float*)d_in[9];
    const float* ca_up_w   = (const float*)d_in[10];
    const float* ca_up_b   = (const float*)d_in[11];
    const float* sr_w      = (const float*)d_in[12];
    const float* sr_b      = (const float*)d_in[13];
    const float* st_w      = (const float*)d_in[14];
    const float* st_b      = (const float*)d_in[15];
    float* out = (float*)d_out;
    float* ws  = (float*)d_ws;

    // ws float layout:
    //   [0,1024)        means (tau*512 + b*128 + c)
    //   [1024,2048)     ynorm
    //   [2048,12288)    conv partial maxes: ((b*128+g)*10+yt)*2 + oc
    //   [12288,14336)   coefs: alpha_r | alpha_t | wr | wt  (each 512)
    //   [14336,26880)   wpk: packed f16x2 conv weights [g][ky][oc][kx]
    unsigned* wpk = (unsigned*)(ws + 14336);
    pack_w_kernel<<<49, 256, 0, stream>>>(dw_w, wpk);
    mean_kernel<<<1024, 256, 0, stream>>>(RGB, T, ws);
    mlp_kernel<<<8, 256, 0, stream>>>(ws, fp_down_w, fp_down_b, fp_up_w, fp_up_b, ws + 1024);
    conv_max_kernel<<<dim3(NYT, 128, 4), 256, 0, stream>>>(RGB, T, wpk, ws + 1024, ws + 2048);
    att_kernel<<<1, 256, 0, stream>>>(ws + 1024, ws + 2048, dw_b, ca_down_w, ca_down_b,
                                      ca_up_w, ca_up_b, sr_w, st_w, ws + 12288);
    fuse_kernel<<<dim3(100, 4), 256, 0, stream>>>(RGB, T, ws + 12288, sr_b, st_b, out);
}